// Round 14
// baseline (122.544 us; speedup 1.0000x reference)
//
#include <hip/hip_runtime.h>

#define NN 50000
#define TT 12
#define QQ 3
#define HH 64
#define KK 32
#define TQ 36    // T*Q
#define PW 9     // 8-byte words per 72B bf16 row; thread = (node, p<9)
#define NLEV 4

#define FB 256        // fused kernel: blocks (<=1/CU -> co-residency guaranteed)
#define FT 512        // threads per block (8 waves)
#define FN (FB * FT)  // 131072 threads, grid-stride over 450000 items
#define ITEMS (NN * PW)

// Barrier counters in device globals: zeroed at module load, and each complete
// kernel execution returns them to zero (self-resetting), so graph replays and
// the 0xAA workspace poison cannot corrupt them.
__device__ unsigned g_bar0, g_bar1, g_fin;

__device__ __forceinline__ float bf2f(unsigned int u16) {
    union { unsigned int i; float f; } c; c.i = u16 << 16; return c.f;
}
__device__ __forceinline__ unsigned short f2bf(float f) {
    union { float f; unsigned int i; } c; c.f = f;
    unsigned int u = c.i;
    u += 0x7FFFu + ((u >> 16) & 1u);
    return (unsigned short)(u >> 16);
}

// ---------------------------------------------------------------------------
// Projection in XW-space (bf16 out) — R12 verbatim (proven 63.6/64.2).
// XW = (gnn@w + b) * scaler; level recursion in XW-space is a pure gather-sum.
// ---------------------------------------------------------------------------
__global__ __launch_bounds__(256) void proj_xw_kernel(
    const float* __restrict__ gnn, const float* __restrict__ w,
    const float* __restrict__ b, const float* __restrict__ scaler,
    unsigned short* __restrict__ xw, int nrows)
{
    const int lane = threadIdx.x & 63;
    const int sub  = lane & 15;
    const int h0   = sub * 4;

    float wreg[4][3];
#pragma unroll
    for (int j = 0; j < 4; ++j)
#pragma unroll
        for (int q = 0; q < 3; ++q)
            wreg[j][q] = w[(h0 + j) * 3 + q];
    const float b0 = b[0], b1 = b[1], b2 = b[2];

    const int gwave  = (blockIdx.x * blockDim.x + threadIdx.x) >> 6;
    const int nwaves = (gridDim.x * blockDim.x) >> 6;
    const int nquads = nrows >> 2;

    for (int quad = gwave; quad < nquads; quad += nwaves) {
        const float4 g = *reinterpret_cast<const float4*>(gnn + (size_t)quad * 256 + lane * 4);
        float a0 = g.x * wreg[0][0] + g.y * wreg[1][0] + g.z * wreg[2][0] + g.w * wreg[3][0];
        float a1 = g.x * wreg[0][1] + g.y * wreg[1][1] + g.z * wreg[2][1] + g.w * wreg[3][1];
        float a2 = g.x * wreg[0][2] + g.y * wreg[1][2] + g.z * wreg[2][2] + g.w * wreg[3][2];
#pragma unroll
        for (int off = 8; off > 0; off >>= 1) {
            a0 += __shfl_down(a0, off);
            a1 += __shfl_down(a1, off);
            a2 += __shfl_down(a2, off);
        }
        if (sub == 0) {
            const int row = quad * 4 + (lane >> 4);   // row = node*T + t
            const float s = scaler[row];
            xw[row * 3 + 0] = f2bf((a0 + b0) * s);
            xw[row * 3 + 1] = f2bf((a1 + b1) * s);
            xw[row * 3 + 2] = f2bf((a2 + b2) * s);
        }
    }
}

// ---------------------------------------------------------------------------
// Gather-sum for one uint2 (4 bf16): 32 dwordx2 gathers all issued before any
// use (R9/R11's proven pattern), convert+accumulate afterwards.
// ---------------------------------------------------------------------------
__device__ __forceinline__ float4 gather_sum_quad(
    const uint2* __restrict__ cur64, const int* __restrict__ keybom,
    int node, int p)
{
    const int4* kb4 = reinterpret_cast<const int4*>(keybom + (size_t)node * KK);
    int keys[KK];
#pragma unroll
    for (int kk = 0; kk < KK / 4; ++kk) {
        const int4 k4 = kb4[kk];
        keys[kk * 4 + 0] = k4.x; keys[kk * 4 + 1] = k4.y;
        keys[kk * 4 + 2] = k4.z; keys[kk * 4 + 3] = k4.w;
    }
    uint2 u[KK];
#pragma unroll
    for (int k = 0; k < KK; ++k) {
        const int key = keys[k];
        u[k] = (key >= 0) ? cur64[(size_t)key * PW + p] : make_uint2(0u, 0u);
    }
    float a0 = 0.f, a1 = 0.f, a2 = 0.f, a3 = 0.f;
#pragma unroll
    for (int k = 0; k < KK; ++k) {
        a0 += bf2f(u[k].x & 0xFFFFu);
        a1 += bf2f(u[k].x >> 16);
        a2 += bf2f(u[k].y & 0xFFFFu);
        a3 += bf2f(u[k].y >> 16);
    }
    return make_float4(a0, a1, a2, a3);
}

// ---------------------------------------------------------------------------
// Grid barrier: flat agent-scope arrive + spin (the grid.sync mechanism).
// Release on arrive makes this block's phase writes visible device-wide;
// acquire on the spin load invalidates stale L1/L2 before the next phase.
// Last arriver resets the PREVIOUS barrier's counter (all blocks passed it).
// ---------------------------------------------------------------------------
__device__ __forceinline__ void gbar(unsigned* ctr, unsigned* prev)
{
    __syncthreads();
    if (threadIdx.x == 0) {
        const unsigned my = __hip_atomic_fetch_add(ctr, 1u, __ATOMIC_RELEASE,
                                                   __HIP_MEMORY_SCOPE_AGENT);
        if (prev != nullptr && my == FB - 1)
            __hip_atomic_store(prev, 0u, __ATOMIC_RELAXED,
                               __HIP_MEMORY_SCOPE_AGENT);
        while (__hip_atomic_load(ctr, __ATOMIC_ACQUIRE,
                                 __HIP_MEMORY_SCOPE_AGENT) < FB)
            __builtin_amdgcn_s_sleep(1);
    }
    __syncthreads();
}

// ---------------------------------------------------------------------------
// One level phase (ping-pong), grid-strided over (node, p) items.
// ---------------------------------------------------------------------------
__device__ __forceinline__ void level_phase(
    const uint2* __restrict__ src, uint2* __restrict__ dst,
    const int* __restrict__ keybom, const int* __restrict__ lvl,
    int level, int gtid)
{
    for (int idx = gtid; idx < ITEMS; idx += FN) {
        const int node = idx / PW;
        const int p    = idx - node * PW;
        if (lvl[node] != level) {           // pass-through: 8B copy
            dst[idx] = src[idx];
            continue;
        }
        const float4 s = gather_sum_quad(src, keybom, node, p);
        dst[idx] = make_uint2(
            (unsigned)f2bf(s.x) | ((unsigned)f2bf(s.y) << 16),
            (unsigned)f2bf(s.z) | ((unsigned)f2bf(s.w) << 16));
    }
}

// ---------------------------------------------------------------------------
// Final phase: level 3 fused with XW->out (divide by scaler), fp32 float4.
// ---------------------------------------------------------------------------
__device__ __forceinline__ void final_phase(
    const uint2* __restrict__ src, const float* __restrict__ scaler,
    const int* __restrict__ keybom, const int* __restrict__ lvl,
    float* __restrict__ out, int gtid)
{
    for (int idx = gtid; idx < ITEMS; idx += FN) {
        const int node = idx / PW;
        const int p    = idx - node * PW;
        float4 v;
        if (lvl[node] != 3) {
            const uint2 u = src[idx];
            v = make_float4(bf2f(u.x & 0xFFFFu), bf2f(u.x >> 16),
                            bf2f(u.y & 0xFFFFu), bf2f(u.y >> 16));
        } else {
            v = gather_sum_quad(src, keybom, node, p);
        }
        const int e0 = node * TQ + 4 * p;
        const float4 r = make_float4(v.x / scaler[(e0 + 0) / 3],
                                     v.y / scaler[(e0 + 1) / 3],
                                     v.z / scaler[(e0 + 2) / 3],
                                     v.w / scaler[(e0 + 3) / 3]);
        *reinterpret_cast<float4*>(out + e0) = r;   // 144n + 16p: 16B-aligned
    }
}

// ---------------------------------------------------------------------------
// Fused L1 | bar | L2 | bar | L3+out. 256 blocks x 512 thr: co-resident by
// construction (8 waves/block vs 32-wave/CU cap), so the barrier cannot hang.
// ---------------------------------------------------------------------------
__global__ __launch_bounds__(FT) void fused_levels_kernel(
    uint2* bufA, uint2* bufB, const float* __restrict__ scaler,
    const int* __restrict__ keybom, const int* __restrict__ lvl,
    float* __restrict__ out)
{
    const int gtid = blockIdx.x * FT + threadIdx.x;

    level_phase(bufA, bufB, keybom, lvl, 1, gtid);
    gbar(&g_bar0, nullptr);
    level_phase(bufB, bufA, keybom, lvl, 2, gtid);
    gbar(&g_bar1, &g_bar0);
    final_phase(bufA, scaler, keybom, lvl, out, gtid);

    // self-reset for graph replay: last finisher zeroes bar1 + fin
    __syncthreads();
    if (threadIdx.x == 0) {
        const unsigned my = __hip_atomic_fetch_add(&g_fin, 1u, __ATOMIC_RELEASE,
                                                   __HIP_MEMORY_SCOPE_AGENT);
        if (my == FB - 1) {
            __hip_atomic_store(&g_bar1, 0u, __ATOMIC_RELAXED,
                               __HIP_MEMORY_SCOPE_AGENT);
            __hip_atomic_store(&g_fin, 0u, __ATOMIC_RELAXED,
                               __HIP_MEMORY_SCOPE_AGENT);
        }
    }
}

extern "C" void kernel_launch(void* const* d_in, const int* in_sizes, int n_in,
                              void* d_out, int out_size, void* d_ws, size_t ws_size,
                              hipStream_t stream)
{
    const float* gnn    = (const float*)d_in[0];
    const float* w      = (const float*)d_in[1];
    const float* b      = (const float*)d_in[2];
    const float* scaler = (const float*)d_in[3];
    const int*   keybom = (const int*)d_in[4];
    const int*   lvl    = (const int*)d_in[5];
    float* out = (float*)d_out;

    char* ws = (char*)d_ws;
    unsigned short* bufA = (unsigned short*)ws;                         // 3.6 MB
    unsigned short* bufB = (unsigned short*)(ws + (size_t)NN * TQ * 2); // 3.6 MB

    proj_xw_kernel<<<2048, 256, 0, stream>>>(gnn, w, b, scaler, bufA, NN * TT);
    fused_levels_kernel<<<FB, FT, 0, stream>>>((uint2*)bufA, (uint2*)bufB,
                                               scaler, keybom, lvl, out);
}

// Round 15
// 76.859 us; speedup vs baseline: 1.5944x; 1.5944x over previous
//
#include <hip/hip_runtime.h>

#define NN 50000
#define TT 12
#define QQ 3
#define HH 64
#define KK 32
#define TQ 36    // T*Q
#define EB 64    // encoded row bytes: dw0-8 = 36 int8, dw9 = fp32 row scale, dw10-15 pad
#define RU 8     // uint2 per encoded row
#define NLEV 4

// R15 model: levels are bound by L1/TCP cache-LINE request rate (R12 null on
// instr/wave count; R11 win from sector cut; R14 fused counters show levels are
// NOT HBM-bound). bf16 72B rows = 2 lines/key. This 64B int8 row = 1 line/key,
// scale rides in the SAME line (R13 paid a second load for it -> no win).

__device__ __forceinline__ float bf2f(unsigned int u16) {
    union { unsigned int i; float f; } c; c.i = u16 << 16; return c.f;
}
__device__ __forceinline__ unsigned short f2bf(float f) {
    union { float f; unsigned int i; } c; c.f = f;
    unsigned int u = c.i;
    u += 0x7FFFu + ((u >> 16) & 1u);
    return (unsigned short)(u >> 16);
}
__device__ __forceinline__ unsigned int pack4(float v0, float v1, float v2,
                                              float v3, float inv) {
    int q0 = (int)rintf(v0 * inv), q1 = (int)rintf(v1 * inv);
    int q2 = (int)rintf(v2 * inv), q3 = (int)rintf(v3 * inv);
    q0 = q0 > 127 ? 127 : (q0 < -127 ? -127 : q0);
    q1 = q1 > 127 ? 127 : (q1 < -127 ? -127 : q1);
    q2 = q2 > 127 ? 127 : (q2 < -127 ? -127 : q2);
    q3 = q3 > 127 ? 127 : (q3 < -127 ? -127 : q3);
    return (unsigned int)(q0 & 255) | ((unsigned int)(q1 & 255) << 8) |
           ((unsigned int)(q2 & 255) << 16) | ((unsigned int)(q3 & 255) << 24);
}
__device__ __forceinline__ float dec(unsigned int u, int j) {
    return (float)(int)(signed char)(u >> (8 * j));
}

// ---------------------------------------------------------------------------
// Projection in XW-space (bf16 out) — R12 verbatim. XW = (gnn@w + b)*scaler;
// level recursion in XW-space is a pure gather-sum (scaler cancels).
// ---------------------------------------------------------------------------
__global__ __launch_bounds__(256) void proj_xw_kernel(
    const float* __restrict__ gnn, const float* __restrict__ w,
    const float* __restrict__ b, const float* __restrict__ scaler,
    unsigned short* __restrict__ xw, int nrows)
{
    const int lane = threadIdx.x & 63;
    const int sub  = lane & 15;
    const int h0   = sub * 4;

    float wreg[4][3];
#pragma unroll
    for (int j = 0; j < 4; ++j)
#pragma unroll
        for (int q = 0; q < 3; ++q)
            wreg[j][q] = w[(h0 + j) * 3 + q];
    const float b0 = b[0], b1 = b[1], b2 = b[2];

    const int gwave  = (blockIdx.x * blockDim.x + threadIdx.x) >> 6;
    const int nwaves = (gridDim.x * blockDim.x) >> 6;
    const int nquads = nrows >> 2;

    for (int quad = gwave; quad < nquads; quad += nwaves) {
        const float4 g = *reinterpret_cast<const float4*>(gnn + (size_t)quad * 256 + lane * 4);
        float a0 = g.x * wreg[0][0] + g.y * wreg[1][0] + g.z * wreg[2][0] + g.w * wreg[3][0];
        float a1 = g.x * wreg[0][1] + g.y * wreg[1][1] + g.z * wreg[2][1] + g.w * wreg[3][1];
        float a2 = g.x * wreg[0][2] + g.y * wreg[1][2] + g.z * wreg[2][2] + g.w * wreg[3][2];
#pragma unroll
        for (int off = 8; off > 0; off >>= 1) {
            a0 += __shfl_down(a0, off);
            a1 += __shfl_down(a1, off);
            a2 += __shfl_down(a2, off);
        }
        if (sub == 0) {
            const int row = quad * 4 + (lane >> 4);   // row = node*T + t
            const float s = scaler[row];
            xw[row * 3 + 0] = f2bf((a0 + b0) * s);
            xw[row * 3 + 1] = f2bf((a1 + b1) * s);
            xw[row * 3 + 2] = f2bf((a2 + b2) * s);
        }
    }
}

// ---------------------------------------------------------------------------
// Encode: thread = node. Read 36 bf16 (9 uint2, 72B row), row absmax,
// quantize int8 (scale = max/127), write one 64B-aligned row (pads zeroed
// for determinism).
// ---------------------------------------------------------------------------
__global__ __launch_bounds__(256) void encode_kernel(
    const unsigned short* __restrict__ xw, unsigned char* __restrict__ E)
{
    const int node = blockIdx.x * blockDim.x + threadIdx.x;
    if (node >= NN) return;
    const uint2* r2 = reinterpret_cast<const uint2*>(xw) + (size_t)node * 9;
    float v[36];
#pragma unroll
    for (int i = 0; i < 9; ++i) {
        const uint2 u = r2[i];
        v[i * 4 + 0] = bf2f(u.x & 0xFFFFu);
        v[i * 4 + 1] = bf2f(u.x >> 16);
        v[i * 4 + 2] = bf2f(u.y & 0xFFFFu);
        v[i * 4 + 3] = bf2f(u.y >> 16);
    }
    float mm = 0.0f;
#pragma unroll
    for (int i = 0; i < 36; ++i) mm = fmaxf(mm, fabsf(v[i]));
    const float s   = mm * (1.0f / 127.0f);
    const float inv = mm > 0.0f ? 127.0f / mm : 0.0f;
    unsigned int d[9];
#pragma unroll
    for (int i = 0; i < 9; ++i)
        d[i] = pack4(v[i * 4], v[i * 4 + 1], v[i * 4 + 2], v[i * 4 + 3], inv);

    uint4* o = reinterpret_cast<uint4*>(E + (size_t)node * EB);
    o[0] = make_uint4(d[0], d[1], d[2], d[3]);
    o[1] = make_uint4(d[4], d[5], d[6], d[7]);
    o[2] = make_uint4(d[8], __float_as_uint(s), 0u, 0u);
    o[3] = make_uint4(0u, 0u, 0u, 0u);
}

// ---------------------------------------------------------------------------
// Shared gather core: 8 lanes per node, lane p loads dwords {2p,2p+1} of each
// key row (ONE 64B line per key per node). Keys: one coalesced int4 per lane
// (lane p owns keys 4p..4p+3), distributed by shfl. Scale = dword 9 rides in
// lane 4's uint2 -> shfl broadcast, no extra load. acc[0..7] fp32.
// Lanes 5-7 read zero pads -> contribute nothing.
// ---------------------------------------------------------------------------
__device__ __forceinline__ void gather_sum_i8(
    const unsigned char* __restrict__ Ein, const int* __restrict__ keybom,
    int node, int p, int gb, float acc[8])
{
    const int4 mine = reinterpret_cast<const int4*>(keybom + (size_t)node * KK)[p];
    const uint2* E2 = reinterpret_cast<const uint2*>(Ein);
    uint2 u[KK];
#pragma unroll
    for (int k = 0; k < KK; ++k) {
        const int c = k & 3;
        const int kv = (c == 0) ? mine.x : (c == 1) ? mine.y : (c == 2) ? mine.z : mine.w;
        const int key = __shfl(kv, gb + (k >> 2));
        u[k] = (key >= 0) ? E2[(size_t)key * RU + p] : make_uint2(0u, 0u);
    }
#pragma unroll
    for (int k = 0; k < KK; ++k) {
        const float s = __int_as_float(__shfl((int)u[k].y, gb + 4));
        acc[0] = fmaf(dec(u[k].x, 0), s, acc[0]);
        acc[1] = fmaf(dec(u[k].x, 1), s, acc[1]);
        acc[2] = fmaf(dec(u[k].x, 2), s, acc[2]);
        acc[3] = fmaf(dec(u[k].x, 3), s, acc[3]);
        acc[4] = fmaf(dec(u[k].y, 0), s, acc[4]);   // p==4: garbage (excluded)
        acc[5] = fmaf(dec(u[k].y, 1), s, acc[5]);
        acc[6] = fmaf(dec(u[k].y, 2), s, acc[6]);
        acc[7] = fmaf(dec(u[k].y, 3), s, acc[7]);
    }
}

// ---------------------------------------------------------------------------
// One level, ping-pong over encoded state. 8 lanes/node, 8 nodes/wave.
// ---------------------------------------------------------------------------
__global__ __launch_bounds__(256) void level_i8_kernel(
    const unsigned char* __restrict__ Ein, const int* __restrict__ keybom,
    const int* __restrict__ lvl, unsigned char* __restrict__ Eout, int level)
{
    const int tid  = blockIdx.x * 256 + threadIdx.x;
    const int lane = threadIdx.x & 63;
    const int grp  = lane >> 3;
    const int p    = lane & 7;
    const int gb   = lane & 56;
    const int node = (tid >> 6) * 8 + grp;
    if (node >= NN) return;

    const uint2* rin  = reinterpret_cast<const uint2*>(Ein + (size_t)node * EB);
    uint2*       rout = reinterpret_cast<uint2*>(Eout + (size_t)node * EB);

    if (lvl[node] != level) {            // pass-through: full 64B row copy
        rout[p] = rin[p];
        return;
    }

    float acc[8] = {0.f, 0.f, 0.f, 0.f, 0.f, 0.f, 0.f, 0.f};
    gather_sum_i8(Ein, keybom, node, p, gb, acc);

    float m = 0.0f;
#pragma unroll
    for (int j = 0; j < 8; ++j) {
        const bool valid = (p < 4) || (p == 4 && j < 4);
        if (valid) m = fmaxf(m, fabsf(acc[j]));
    }
    m = fmaxf(m, __shfl_xor(m, 1));
    m = fmaxf(m, __shfl_xor(m, 2));
    m = fmaxf(m, __shfl_xor(m, 4));

    const float s   = m * (1.0f / 127.0f);
    const float inv = m > 0.0f ? 127.0f / m : 0.0f;
    if (p < 4) {
        rout[p] = make_uint2(pack4(acc[0], acc[1], acc[2], acc[3], inv),
                             pack4(acc[4], acc[5], acc[6], acc[7], inv));
    } else if (p == 4) {
        rout[4] = make_uint2(pack4(acc[0], acc[1], acc[2], acc[3], inv),
                             __float_as_uint(s));
    } else {
        rout[p] = make_uint2(0u, 0u);    // keep pads zero (determinism)
    }
}

// ---------------------------------------------------------------------------
// Final level (3) fused with decode + divide-by-scaler, fp32 float4 stores.
// ---------------------------------------------------------------------------
__global__ __launch_bounds__(256) void level_final_i8_kernel(
    const unsigned char* __restrict__ Ein, const float* __restrict__ scaler,
    const int* __restrict__ keybom, const int* __restrict__ lvl,
    float* __restrict__ out)
{
    const int tid  = blockIdx.x * 256 + threadIdx.x;
    const int lane = threadIdx.x & 63;
    const int grp  = lane >> 3;
    const int p    = lane & 7;
    const int gb   = lane & 56;
    const int node = (tid >> 6) * 8 + grp;
    if (node >= NN) return;

    const uint2* rin = reinterpret_cast<const uint2*>(Ein + (size_t)node * EB);
    float vals[8];

    if (lvl[node] != 3) {
        const uint2 u = rin[p];
        const float s = __int_as_float(__shfl((int)u.y, gb + 4));
        vals[0] = dec(u.x, 0) * s; vals[1] = dec(u.x, 1) * s;
        vals[2] = dec(u.x, 2) * s; vals[3] = dec(u.x, 3) * s;
        vals[4] = dec(u.y, 0) * s; vals[5] = dec(u.y, 1) * s;
        vals[6] = dec(u.y, 2) * s; vals[7] = dec(u.y, 3) * s;
    } else {
        float acc[8] = {0.f, 0.f, 0.f, 0.f, 0.f, 0.f, 0.f, 0.f};
        gather_sum_i8(Ein, keybom, node, p, gb, acc);
#pragma unroll
        for (int j = 0; j < 8; ++j) vals[j] = acc[j];
    }

    if (p < 4) {
        const int e0 = node * TQ + 8 * p;
        const float4 r0 = make_float4(vals[0] / scaler[(e0 + 0) / 3],
                                      vals[1] / scaler[(e0 + 1) / 3],
                                      vals[2] / scaler[(e0 + 2) / 3],
                                      vals[3] / scaler[(e0 + 3) / 3]);
        const float4 r1 = make_float4(vals[4] / scaler[(e0 + 4) / 3],
                                      vals[5] / scaler[(e0 + 5) / 3],
                                      vals[6] / scaler[(e0 + 6) / 3],
                                      vals[7] / scaler[(e0 + 7) / 3]);
        *reinterpret_cast<float4*>(out + e0)     = r0;  // 144n+32p: aligned
        *reinterpret_cast<float4*>(out + e0 + 4) = r1;
    } else if (p == 4) {
        const int e0 = node * TQ + 32;
        const float4 r0 = make_float4(vals[0] / scaler[(e0 + 0) / 3],
                                      vals[1] / scaler[(e0 + 1) / 3],
                                      vals[2] / scaler[(e0 + 2) / 3],
                                      vals[3] / scaler[(e0 + 3) / 3]);
        *reinterpret_cast<float4*>(out + e0) = r0;
    }
}

extern "C" void kernel_launch(void* const* d_in, const int* in_sizes, int n_in,
                              void* d_out, int out_size, void* d_ws, size_t ws_size,
                              hipStream_t stream)
{
    const float* gnn    = (const float*)d_in[0];
    const float* w      = (const float*)d_in[1];
    const float* b      = (const float*)d_in[2];
    const float* scaler = (const float*)d_in[3];
    const int*   keybom = (const int*)d_in[4];
    const int*   lvl    = (const int*)d_in[5];
    float* out = (float*)d_out;

    char* ws = (char*)d_ws;
    unsigned short* XW = (unsigned short*)ws;                    // 3.6 MB bf16
    unsigned char*  E0 = (unsigned char*)(ws + (size_t)NN * TQ * 2);  // 3.2 MB
    unsigned char*  E1 = E0 + (size_t)NN * EB;                        // 3.2 MB

    proj_xw_kernel<<<2048, 256, 0, stream>>>(gnn, w, b, scaler, XW, NN * TT);
    encode_kernel<<<(NN + 255) / 256, 256, 0, stream>>>(XW, E0);

    const int lblocks = (NN * 8 + 255) / 256;   // 8 lanes per node
    level_i8_kernel<<<lblocks, 256, 0, stream>>>(E0, keybom, lvl, E1, 1);
    level_i8_kernel<<<lblocks, 256, 0, stream>>>(E1, keybom, lvl, E0, 2);
    level_final_i8_kernel<<<lblocks, 256, 0, stream>>>(E0, scaler, keybom, lvl, out);
}

// Round 16
// 73.734 us; speedup vs baseline: 1.6620x; 1.0424x over previous
//
#include <hip/hip_runtime.h>

#define NN 50000
#define TT 12
#define QQ 3
#define HH 64
#define KK 32
#define TQ 36    // T*Q
#define PW 9     // uint2 words per 72B bf16 row; thread = (node, p<9)
#define NLEV 4

// R16 structure: write-once F/P buffers, no ping-pong pass-through.
//   P[node] = proj XW (bf16, immutable after proj)
//   F[node] = the node's once-written level-update result (XW space)
// Key Y read at level L:  F[Y] iff 1 <= lvl[Y] < L, else P[Y].
// prep encodes keybom once: enc = key | lvl'<<16 (lvl'=3 if lvl==0, so lvl-0
// keys never select F). Level-L kernels touch only active nodes.
__device__ __forceinline__ float bf2f(unsigned int u16) {
    union { unsigned int i; float f; } c; c.i = u16 << 16; return c.f;
}
__device__ __forceinline__ unsigned short f2bf(float f) {
    union { float f; unsigned int i; } c; c.f = f;
    unsigned int u = c.i;
    u += 0x7FFFu + ((u >> 16) & 1u);
    return (unsigned short)(u >> 16);
}

// ---------------------------------------------------------------------------
// Prep: enc[n][k] = keybom<0 ? -1 : key | lvl'<<16   (lvl' = lvl==0 ? 3 : lvl)
// ---------------------------------------------------------------------------
__global__ __launch_bounds__(256) void prep_kernel(
    const int* __restrict__ keybom, const int* __restrict__ lvl,
    int* __restrict__ enc)
{
    const int idx = blockIdx.x * 256 + threadIdx.x;
    if (idx >= NN * KK) return;
    const int key = keybom[idx];
    int e = -1;
    if (key >= 0) {
        int l = lvl[key];
        l = (l == 0) ? 3 : l;
        e = key | (l << 16);      // key < 50000 < 2^16
    }
    enc[idx] = e;
}

// ---------------------------------------------------------------------------
// Projection in XW-space (bf16 out) — R12 verbatim (proven). P = (gnn@w+b)*sc.
// ---------------------------------------------------------------------------
__global__ __launch_bounds__(256) void proj_xw_kernel(
    const float* __restrict__ gnn, const float* __restrict__ w,
    const float* __restrict__ b, const float* __restrict__ scaler,
    unsigned short* __restrict__ xw, int nrows)
{
    const int lane = threadIdx.x & 63;
    const int sub  = lane & 15;
    const int h0   = sub * 4;

    float wreg[4][3];
#pragma unroll
    for (int j = 0; j < 4; ++j)
#pragma unroll
        for (int q = 0; q < 3; ++q)
            wreg[j][q] = w[(h0 + j) * 3 + q];
    const float b0 = b[0], b1 = b[1], b2 = b[2];

    const int gwave  = (blockIdx.x * blockDim.x + threadIdx.x) >> 6;
    const int nwaves = (gridDim.x * blockDim.x) >> 6;
    const int nquads = nrows >> 2;

    for (int quad = gwave; quad < nquads; quad += nwaves) {
        const float4 g = *reinterpret_cast<const float4*>(gnn + (size_t)quad * 256 + lane * 4);
        float a0 = g.x * wreg[0][0] + g.y * wreg[1][0] + g.z * wreg[2][0] + g.w * wreg[3][0];
        float a1 = g.x * wreg[0][1] + g.y * wreg[1][1] + g.z * wreg[2][1] + g.w * wreg[3][1];
        float a2 = g.x * wreg[0][2] + g.y * wreg[1][2] + g.z * wreg[2][2] + g.w * wreg[3][2];
#pragma unroll
        for (int off = 8; off > 0; off >>= 1) {
            a0 += __shfl_down(a0, off);
            a1 += __shfl_down(a1, off);
            a2 += __shfl_down(a2, off);
        }
        if (sub == 0) {
            const int row = quad * 4 + (lane >> 4);   // row = node*T + t
            const float s = scaler[row];
            xw[row * 3 + 0] = f2bf((a0 + b0) * s);
            xw[row * 3 + 1] = f2bf((a1 + b1) * s);
            xw[row * 3 + 2] = f2bf((a2 + b2) * s);
        }
    }
}

// ---------------------------------------------------------------------------
// Gather-sum (F/P select): 32 dwordx2 gathers all issued before any use
// (R9/R11/R12's proven pattern); source buffer picked per key by the
// prep-encoded level (2 cndmasks, no extra memory dependency).
// ---------------------------------------------------------------------------
__device__ __forceinline__ float4 gather_FP(
    const uint2* __restrict__ P2, const uint2* __restrict__ F2,
    const int* __restrict__ enc, int node, int p, int level)
{
    const int4* kb4 = reinterpret_cast<const int4*>(enc + (size_t)node * KK);
    int e[KK];
#pragma unroll
    for (int kk = 0; kk < KK / 4; ++kk) {
        const int4 k4 = kb4[kk];
        e[kk * 4 + 0] = k4.x; e[kk * 4 + 1] = k4.y;
        e[kk * 4 + 2] = k4.z; e[kk * 4 + 3] = k4.w;
    }
    uint2 u[KK];
#pragma unroll
    for (int k = 0; k < KK; ++k) {
        const int ee  = e[k];
        const int key = ee & 0xFFFF;
        const uint2* src = (((ee >> 16) & 3) < level) ? F2 : P2;
        u[k] = (ee >= 0) ? src[(size_t)key * PW + p] : make_uint2(0u, 0u);
    }
    float a0 = 0.f, a1 = 0.f, a2 = 0.f, a3 = 0.f;
#pragma unroll
    for (int k = 0; k < KK; ++k) {
        a0 += bf2f(u[k].x & 0xFFFFu);
        a1 += bf2f(u[k].x >> 16);
        a2 += bf2f(u[k].y & 0xFFFFu);
        a3 += bf2f(u[k].y >> 16);
    }
    return make_float4(a0, a1, a2, a3);
}

// ---------------------------------------------------------------------------
// Level L in {1,2}: active nodes only; write this node's once-only F row.
// No pass-through, no ping-pong.
// ---------------------------------------------------------------------------
__global__ __launch_bounds__(256) void levelF_kernel(
    const uint2* __restrict__ P2, uint2* F2, const int* __restrict__ enc,
    const int* __restrict__ lvl, int level)
{
    const int idx  = blockIdx.x * 256 + threadIdx.x;
    if (idx >= NN * PW) return;
    const int node = idx / PW;
    if (lvl[node] != level) return;
    const int p    = idx - node * PW;

    const float4 s = gather_FP(P2, F2, enc, node, p, level);
    F2[(size_t)node * PW + p] = make_uint2(
        (unsigned)f2bf(s.x) | ((unsigned)f2bf(s.y) << 16),
        (unsigned)f2bf(s.z) | ((unsigned)f2bf(s.w) << 16));
}

// ---------------------------------------------------------------------------
// Level 3 fused with the XW -> out conversion for ALL nodes:
//   lvl==3 : gather;  lvl in {1,2} : F row;  lvl==0 : P row.  Then /scaler.
// ---------------------------------------------------------------------------
__global__ __launch_bounds__(256) void level3_final_kernel(
    const uint2* __restrict__ P2, const uint2* __restrict__ F2,
    const int* __restrict__ enc, const int* __restrict__ lvl,
    const float* __restrict__ scaler, float* __restrict__ out)
{
    const int idx  = blockIdx.x * 256 + threadIdx.x;
    if (idx >= NN * PW) return;
    const int node = idx / PW;
    const int p    = idx - node * PW;
    const int l    = lvl[node];

    float4 v;
    if (l == 3) {
        v = gather_FP(P2, F2, enc, node, p, 3);
    } else {
        const uint2 u = ((l >= 1) ? F2 : P2)[(size_t)node * PW + p];
        v = make_float4(bf2f(u.x & 0xFFFFu), bf2f(u.x >> 16),
                        bf2f(u.y & 0xFFFFu), bf2f(u.y >> 16));
    }
    const int e0 = node * TQ + 4 * p;
    const float4 r = make_float4(v.x / scaler[(e0 + 0) / 3],
                                 v.y / scaler[(e0 + 1) / 3],
                                 v.z / scaler[(e0 + 2) / 3],
                                 v.w / scaler[(e0 + 3) / 3]);
    *reinterpret_cast<float4*>(out + e0) = r;   // 144n + 16p: 16B-aligned
}

extern "C" void kernel_launch(void* const* d_in, const int* in_sizes, int n_in,
                              void* d_out, int out_size, void* d_ws, size_t ws_size,
                              hipStream_t stream)
{
    const float* gnn    = (const float*)d_in[0];
    const float* w      = (const float*)d_in[1];
    const float* b      = (const float*)d_in[2];
    const float* scaler = (const float*)d_in[3];
    const int*   keybom = (const int*)d_in[4];
    const int*   lvl    = (const int*)d_in[5];
    float* out = (float*)d_out;

    char* ws = (char*)d_ws;
    int*            encb = (int*)ws;                                  // 6.4 MB
    unsigned short* P    = (unsigned short*)(ws + (size_t)NN * KK * 4);      // 3.6 MB
    unsigned short* F    = (unsigned short*)(ws + (size_t)NN * KK * 4
                                                + (size_t)NN * TQ * 2);      // 3.6 MB

    prep_kernel<<<(NN * KK + 255) / 256, 256, 0, stream>>>(keybom, lvl, encb);
    proj_xw_kernel<<<2048, 256, 0, stream>>>(gnn, w, b, scaler, P, NN * TT);

    const int blocks = (NN * PW + 255) / 256;
    levelF_kernel<<<blocks, 256, 0, stream>>>((const uint2*)P, (uint2*)F, encb, lvl, 1);
    levelF_kernel<<<blocks, 256, 0, stream>>>((const uint2*)P, (uint2*)F, encb, lvl, 2);
    level3_final_kernel<<<blocks, 256, 0, stream>>>((const uint2*)P, (const uint2*)F,
                                                    encb, lvl, scaler, out);
}

// Round 17
// 71.675 us; speedup vs baseline: 1.7097x; 1.0287x over previous
//
#include <hip/hip_runtime.h>

#define NN 50000
#define TT 12
#define QQ 3
#define HH 64
#define KK 32
#define TQ 36    // T*Q
#define PR 18    // TQ/2 packed bf16 pairs per row
#define NLEV 4

typedef float vf4 __attribute__((ext_vector_type(4)));  // NT-builtin-compatible

// State = XW = out*scaler, bf16, packed 2-per-dword (R11 structure, 63.6us —
// best measured). Level recursion in XW-space is a pure gather-sum (scaler
// cancels). Gathers are DWORD loads, all 32 issued before any use (R9's win);
// conversion happens afterwards on registers.
__device__ __forceinline__ float bf2f(unsigned int u16) {
    union { unsigned int i; float f; } c; c.i = u16 << 16; return c.f;
}
__device__ __forceinline__ unsigned short f2bf(float f) {
    union { float f; unsigned int i; } c; c.f = f;
    unsigned int u = c.i;
    u += 0x7FFFu + ((u >> 16) & 1u);
    return (unsigned short)(u >> 16);
}

// ---------------------------------------------------------------------------
// Projection in XW-space (bf16 out): xw[row*3+q] = (proj+b)[row,q] * sc[row].
// gnn is read NON-TEMPORALLY: 153.6MB single-use stream; the hint reduces
// eviction of the freshly-written xw state from L2/L3 so the level kernels
// hit cache on first touch (R14 counters: ~39MB state re-fetch from HBM).
// ---------------------------------------------------------------------------
__global__ __launch_bounds__(256) void proj_xw_kernel(
    const float* __restrict__ gnn, const float* __restrict__ w,
    const float* __restrict__ b, const float* __restrict__ scaler,
    unsigned short* __restrict__ xw, int nrows)
{
    const int lane = threadIdx.x & 63;
    const int sub  = lane & 15;
    const int h0   = sub * 4;

    float wreg[4][3];
#pragma unroll
    for (int j = 0; j < 4; ++j)
#pragma unroll
        for (int q = 0; q < 3; ++q)
            wreg[j][q] = w[(h0 + j) * 3 + q];
    const float b0 = b[0], b1 = b[1], b2 = b[2];

    const int gwave  = (blockIdx.x * blockDim.x + threadIdx.x) >> 6;
    const int nwaves = (gridDim.x * blockDim.x) >> 6;
    const int nquads = nrows >> 2;

    for (int quad = gwave; quad < nquads; quad += nwaves) {
        const vf4 g = __builtin_nontemporal_load(
            reinterpret_cast<const vf4*>(gnn + (size_t)quad * 256 + lane * 4));
        float a0 = g.x * wreg[0][0] + g.y * wreg[1][0] + g.z * wreg[2][0] + g.w * wreg[3][0];
        float a1 = g.x * wreg[0][1] + g.y * wreg[1][1] + g.z * wreg[2][1] + g.w * wreg[3][1];
        float a2 = g.x * wreg[0][2] + g.y * wreg[1][2] + g.z * wreg[2][2] + g.w * wreg[3][2];
#pragma unroll
        for (int off = 8; off > 0; off >>= 1) {
            a0 += __shfl_down(a0, off);
            a1 += __shfl_down(a1, off);
            a2 += __shfl_down(a2, off);
        }
        if (sub == 0) {
            const int row = quad * 4 + (lane >> 4);   // row = node*T + t
            const float s = scaler[row];
            xw[row * 3 + 0] = f2bf((a0 + b0) * s);
            xw[row * 3 + 1] = f2bf((a1 + b1) * s);
            xw[row * 3 + 2] = f2bf((a2 + b2) * s);
        }
    }
}

// ---------------------------------------------------------------------------
// Gather-sum for one bf16 pair: 32 DWORD gathers all issued before any use
// (preloaded keys via 8x int4), then convert+accumulate on registers.
// ---------------------------------------------------------------------------
__device__ __forceinline__ float2 gather_sum_pair(
    const unsigned int* __restrict__ cur32, const int* __restrict__ keybom,
    int node, int p)
{
    const int4* kb4 = reinterpret_cast<const int4*>(keybom + (size_t)node * KK);
    int keys[KK];
#pragma unroll
    for (int kk = 0; kk < KK / 4; ++kk) {
        const int4 k4 = kb4[kk];
        keys[kk * 4 + 0] = k4.x;
        keys[kk * 4 + 1] = k4.y;
        keys[kk * 4 + 2] = k4.z;
        keys[kk * 4 + 3] = k4.w;
    }
    unsigned int u[KK];
#pragma unroll
    for (int k = 0; k < KK; ++k) {
        const int key = keys[k];
        u[k] = (key >= 0) ? cur32[(size_t)key * PR + p] : 0u;  // 32 dwords in flight
    }
    float l0 = 0.f, l1 = 0.f, h0 = 0.f, h1 = 0.f;
#pragma unroll
    for (int k = 0; k < KK; k += 2) {
        l0 += bf2f(u[k] & 0xFFFFu);
        h0 += bf2f(u[k] >> 16);
        l1 += bf2f(u[k + 1] & 0xFFFFu);
        h1 += bf2f(u[k + 1] >> 16);
    }
    return make_float2(l0 + l1, h0 + h1);
}

// ---------------------------------------------------------------------------
// One level in XW-space, ping-pong. Thread = (node, pair p).
// ---------------------------------------------------------------------------
__global__ __launch_bounds__(256) void level_kernel(
    const unsigned int* __restrict__ cur32, const int* __restrict__ keybom,
    const int* __restrict__ lvl, unsigned int* __restrict__ nxt32, int level)
{
    const int idx  = blockIdx.x * blockDim.x + threadIdx.x;
    if (idx >= NN * PR) return;
    const int node = idx / PR;
    const int p    = idx - node * PR;

    if (lvl[node] != level) {                 // pass-through: dword copy
        nxt32[idx] = cur32[idx];
        return;
    }
    const float2 s = gather_sum_pair(cur32, keybom, node, p);
    nxt32[idx] = (unsigned int)f2bf(s.x) | ((unsigned int)f2bf(s.y) << 16);
}

// ---------------------------------------------------------------------------
// Final level fused with XW -> out conversion: out = XW / scaler, fp32,
// float2 store (elements 2p, 2p+1 of the node's row).
// ---------------------------------------------------------------------------
__global__ __launch_bounds__(256) void level_final_kernel(
    const unsigned int* __restrict__ cur32, const float* __restrict__ scaler,
    const int* __restrict__ keybom, const int* __restrict__ lvl,
    float* __restrict__ out, int level)
{
    const int idx  = blockIdx.x * blockDim.x + threadIdx.x;
    if (idx >= NN * PR) return;
    const int node = idx / PR;
    const int p    = idx - node * PR;

    float v0, v1;
    if (lvl[node] != level) {
        const unsigned int u = cur32[idx];
        v0 = bf2f(u & 0xFFFFu);
        v1 = bf2f(u >> 16);
    } else {
        const float2 s = gather_sum_pair(cur32, keybom, node, p);
        v0 = s.x;
        v1 = s.y;
    }
    const int e0 = node * TQ + 2 * p;               // global element index
    const float2 r = make_float2(v0 / scaler[e0 / 3],
                                 v1 / scaler[(e0 + 1) / 3]);
    *reinterpret_cast<float2*>(out + e0) = r;       // 8B-aligned (144n + 8p)
}

extern "C" void kernel_launch(void* const* d_in, const int* in_sizes, int n_in,
                              void* d_out, int out_size, void* d_ws, size_t ws_size,
                              hipStream_t stream)
{
    const float* gnn    = (const float*)d_in[0];
    const float* w      = (const float*)d_in[1];
    const float* b      = (const float*)d_in[2];
    const float* scaler = (const float*)d_in[3];
    const int*   keybom = (const int*)d_in[4];
    const int*   lvl    = (const int*)d_in[5];
    float* out = (float*)d_out;

    char* ws = (char*)d_ws;
    unsigned short* bufA = (unsigned short*)ws;                         // 3.6 MB
    unsigned short* bufB = (unsigned short*)(ws + (size_t)NN * TQ * 2); // 3.6 MB

    proj_xw_kernel<<<2048, 256, 0, stream>>>(gnn, w, b, scaler, bufA, NN * TT);

    const int blocks = (NN * PR + 255) / 256;
    level_kernel<<<blocks, 256, 0, stream>>>((const unsigned int*)bufA, keybom, lvl,
                                             (unsigned int*)bufB, 1);
    level_kernel<<<blocks, 256, 0, stream>>>((const unsigned int*)bufB, keybom, lvl,
                                             (unsigned int*)bufA, 2);
    level_final_kernel<<<blocks, 256, 0, stream>>>((const unsigned int*)bufA, scaler,
                                                   keybom, lvl, out, 3);
}

// Round 18
// 63.381 us; speedup vs baseline: 1.9334x; 1.1309x over previous
//
#include <hip/hip_runtime.h>

#define NN 50000
#define TT 12
#define QQ 3
#define HH 64
#define KK 32
#define TQ 36    // T*Q
#define PR 18    // TQ/2 packed bf16 pairs per row
#define NLEV 4

// State = XW = out*scaler in bf16, packed 2-per-dword. Level recursion in
// XW-space is a pure gather-sum (scaler cancels; R8 identity). bf16 rows are
// 72B = 2 cache lines (fp32 was 3). Gathers are DWORD loads with all 32
// issued before any use (R9's win); conversion happens after, on registers.
// R17 lesson: NO nontemporal hint on the proj stream (cost +8us: the nt flag
// defeats L2 aggregation of the 64B lane requests into full HBM bursts).
__device__ __forceinline__ float bf2f(unsigned int u16) {
    union { unsigned int i; float f; } c; c.i = u16 << 16; return c.f;
}
__device__ __forceinline__ unsigned short f2bf(float f) {
    union { float f; unsigned int i; } c; c.f = f;
    unsigned int u = c.i;
    u += 0x7FFFu + ((u >> 16) & 1u);
    return (unsigned short)(u >> 16);
}

// ---------------------------------------------------------------------------
// Projection in XW-space (bf16 out): xw[row*3+q] = (proj+b)[row,q] * sc[row].
// ---------------------------------------------------------------------------
__global__ __launch_bounds__(256) void proj_xw_kernel(
    const float* __restrict__ gnn, const float* __restrict__ w,
    const float* __restrict__ b, const float* __restrict__ scaler,
    unsigned short* __restrict__ xw, int nrows)
{
    const int lane = threadIdx.x & 63;
    const int sub  = lane & 15;
    const int h0   = sub * 4;

    float wreg[4][3];
#pragma unroll
    for (int j = 0; j < 4; ++j)
#pragma unroll
        for (int q = 0; q < 3; ++q)
            wreg[j][q] = w[(h0 + j) * 3 + q];
    const float b0 = b[0], b1 = b[1], b2 = b[2];

    const int gwave  = (blockIdx.x * blockDim.x + threadIdx.x) >> 6;
    const int nwaves = (gridDim.x * blockDim.x) >> 6;
    const int nquads = nrows >> 2;

    for (int quad = gwave; quad < nquads; quad += nwaves) {
        const float4 g = *reinterpret_cast<const float4*>(gnn + (size_t)quad * 256 + lane * 4);
        float a0 = g.x * wreg[0][0] + g.y * wreg[1][0] + g.z * wreg[2][0] + g.w * wreg[3][0];
        float a1 = g.x * wreg[0][1] + g.y * wreg[1][1] + g.z * wreg[2][1] + g.w * wreg[3][1];
        float a2 = g.x * wreg[0][2] + g.y * wreg[1][2] + g.z * wreg[2][2] + g.w * wreg[3][2];
#pragma unroll
        for (int off = 8; off > 0; off >>= 1) {
            a0 += __shfl_down(a0, off);
            a1 += __shfl_down(a1, off);
            a2 += __shfl_down(a2, off);
        }
        if (sub == 0) {
            const int row = quad * 4 + (lane >> 4);   // row = node*T + t
            const float s = scaler[row];
            xw[row * 3 + 0] = f2bf((a0 + b0) * s);
            xw[row * 3 + 1] = f2bf((a1 + b1) * s);
            xw[row * 3 + 2] = f2bf((a2 + b2) * s);
        }
    }
}

// ---------------------------------------------------------------------------
// Gather-sum for one bf16 pair: 32 DWORD gathers all issued before any use
// (preloaded keys via 8x int4), then convert+accumulate on registers.
// ---------------------------------------------------------------------------
__device__ __forceinline__ float2 gather_sum_pair(
    const unsigned int* __restrict__ cur32, const int* __restrict__ keybom,
    int node, int p)
{
    const int4* kb4 = reinterpret_cast<const int4*>(keybom + (size_t)node * KK);
    int keys[KK];
#pragma unroll
    for (int kk = 0; kk < KK / 4; ++kk) {
        const int4 k4 = kb4[kk];
        keys[kk * 4 + 0] = k4.x;
        keys[kk * 4 + 1] = k4.y;
        keys[kk * 4 + 2] = k4.z;
        keys[kk * 4 + 3] = k4.w;
    }
    unsigned int u[KK];
#pragma unroll
    for (int k = 0; k < KK; ++k) {
        const int key = keys[k];
        u[k] = (key >= 0) ? cur32[(size_t)key * PR + p] : 0u;  // 32 dwords in flight
    }
    float l0 = 0.f, l1 = 0.f, h0 = 0.f, h1 = 0.f;
#pragma unroll
    for (int k = 0; k < KK; k += 2) {
        l0 += bf2f(u[k] & 0xFFFFu);
        h0 += bf2f(u[k] >> 16);
        l1 += bf2f(u[k + 1] & 0xFFFFu);
        h1 += bf2f(u[k + 1] >> 16);
    }
    return make_float2(l0 + l1, h0 + h1);
}

// ---------------------------------------------------------------------------
// One level in XW-space, ping-pong. Thread = (node, pair p).
// ---------------------------------------------------------------------------
__global__ __launch_bounds__(256) void level_kernel(
    const unsigned int* __restrict__ cur32, const int* __restrict__ keybom,
    const int* __restrict__ lvl, unsigned int* __restrict__ nxt32, int level)
{
    const int idx  = blockIdx.x * blockDim.x + threadIdx.x;
    if (idx >= NN * PR) return;
    const int node = idx / PR;
    const int p    = idx - node * PR;

    if (lvl[node] != level) {                 // pass-through: dword copy
        nxt32[idx] = cur32[idx];
        return;
    }
    const float2 s = gather_sum_pair(cur32, keybom, node, p);
    nxt32[idx] = (unsigned int)f2bf(s.x) | ((unsigned int)f2bf(s.y) << 16);
}

// ---------------------------------------------------------------------------
// Final level fused with XW -> out conversion: out = XW / scaler, fp32,
// float2 store (elements 2p, 2p+1 of the node's row).
// ---------------------------------------------------------------------------
__global__ __launch_bounds__(256) void level_final_kernel(
    const unsigned int* __restrict__ cur32, const float* __restrict__ scaler,
    const int* __restrict__ keybom, const int* __restrict__ lvl,
    float* __restrict__ out, int level)
{
    const int idx  = blockIdx.x * blockDim.x + threadIdx.x;
    if (idx >= NN * PR) return;
    const int node = idx / PR;
    const int p    = idx - node * PR;

    float v0, v1;
    if (lvl[node] != level) {
        const unsigned int u = cur32[idx];
        v0 = bf2f(u & 0xFFFFu);
        v1 = bf2f(u >> 16);
    } else {
        const float2 s = gather_sum_pair(cur32, keybom, node, p);
        v0 = s.x;
        v1 = s.y;
    }
    const int e0 = node * TQ + 2 * p;               // global element index
    const float2 r = make_float2(v0 / scaler[e0 / 3],
                                 v1 / scaler[(e0 + 1) / 3]);
    *reinterpret_cast<float2*>(out + e0) = r;       // 8B-aligned (144n + 8p)
}

extern "C" void kernel_launch(void* const* d_in, const int* in_sizes, int n_in,
                              void* d_out, int out_size, void* d_ws, size_t ws_size,
                              hipStream_t stream)
{
    const float* gnn    = (const float*)d_in[0];
    const float* w      = (const float*)d_in[1];
    const float* b      = (const float*)d_in[2];
    const float* scaler = (const float*)d_in[3];
    const int*   keybom = (const int*)d_in[4];
    const int*   lvl    = (const int*)d_in[5];
    float* out = (float*)d_out;

    char* ws = (char*)d_ws;
    unsigned short* bufA = (unsigned short*)ws;                         // 3.6 MB
    unsigned short* bufB = (unsigned short*)(ws + (size_t)NN * TQ * 2); // 3.6 MB

    proj_xw_kernel<<<2048, 256, 0, stream>>>(gnn, w, b, scaler, bufA, NN * TT);

    const int blocks = (NN * PR + 255) / 256;
    level_kernel<<<blocks, 256, 0, stream>>>((const unsigned int*)bufA, keybom, lvl,
                                             (unsigned int*)bufB, 1);
    level_kernel<<<blocks, 256, 0, stream>>>((const unsigned int*)bufB, keybom, lvl,
                                             (unsigned int*)bufA, 2);
    level_final_kernel<<<blocks, 256, 0, stream>>>((const unsigned int*)bufA, scaler,
                                                   keybom, lvl, out, 3);
}